// Round 12
// baseline (55293.555 us; speedup 1.0000x reference)
//
#include <hip/hip_runtime.h>

// LSTM: N=256, L=2048, IN=8, H1=256, H2=128, OUT=1
// 8 WGs = 4 sets x 2 halves; each WG: 128 hidden units x 4 batch groups (64 samples).
// Gate weights register-resident (144 regs, AGPR-backed); W1 in LDS.
// Cross-WG h-exchange: R4-PROVEN LLC agent atomics only (tagged u64 words
// [h_odd|h_even|tag16], fire-and-forget stores, atomic-load polling).
// Latency hidden by 4-way GROUP INTERLEAVING: while group j's partner data is
// in flight, compute groups j+1..j+3. Prefetch next phase's words at end of
// each phase (compiler places the vmcnt before first use -> true async).
// No census, no XCD placement assumptions, no L1 games. 2 barriers/phase.

typedef __attribute__((ext_vector_type(8))) short short8;
typedef __attribute__((ext_vector_type(4))) float f32x4;

#define LSEQ 2048

__device__ __forceinline__ unsigned short f2bf(float f) {
  unsigned int u = __float_as_uint(f);
  return (unsigned short)((u + 0x7FFFu + ((u >> 16) & 1u)) >> 16);
}
__device__ __forceinline__ float sigm(float x) {
  float e = __builtin_amdgcn_exp2f(-1.44269504089f * x);
  return __builtin_amdgcn_rcpf(1.0f + e);
}
__device__ __forceinline__ float tanh_(float x) {
  float ax = __builtin_fabsf(x);
  float e = __builtin_amdgcn_exp2f(-2.88539008178f * ax);
  float t = (1.0f - e) * __builtin_amdgcn_rcpf(1.0f + e);
  return __builtin_copysignf(t, x);
}
__device__ __forceinline__ void wg_barrier() {
  __asm__ __volatile__("s_waitcnt lgkmcnt(0)" ::: "memory");
  __builtin_amdgcn_s_barrier();
}
__device__ __forceinline__ unsigned long long agent_load(const unsigned long long* a) {
  return __hip_atomic_load(a, __ATOMIC_RELAXED, __HIP_MEMORY_SCOPE_AGENT);
}
__device__ __forceinline__ void agent_store(unsigned long long* a, unsigned long long v) {
  __hip_atomic_store(a, v, __ATOMIC_RELAXED, __HIP_MEMORY_SCOPE_AGENT);
}

// ---------------- prep: frag streams + bias + prev-col + zero pkt ----------------
// gate frag f = hf*288 + nt*9 + kt (nt 0..31): col = (nt>>3)*256 + hf*128 + (nt&7)*16 + (l&15)
//   k = kt*32 + (l>>4)*8 + j; k<256 -> W_hh; 256..263 -> W_ih x-cols; else 0 (prev rank-1)
// w1 frag f = nt*8 + kt (nt 0..7): col = nt*16 + (l&15)
__global__ void prep_kernel(const float* __restrict__ W_ih, const float* __restrict__ W_hh,
                            const float* __restrict__ b_ih, const float* __restrict__ b_hh,
                            const float* __restrict__ W1,
                            unsigned short* __restrict__ wstream,
                            unsigned short* __restrict__ w1stream,
                            float* __restrict__ bias, float* __restrict__ pw,
                            unsigned long long* __restrict__ pkt) {
  int tid = blockIdx.x * 256 + threadIdx.x;
  if (tid < 36864) {
    int f = tid >> 6, l = tid & 63;
    int hf = f / 288, rem = f % 288, nt = rem / 9, kt = rem % 9;
    int col = (nt >> 3) * 256 + hf * 128 + (nt & 7) * 16 + (l & 15);
    int k0 = kt * 32 + (l >> 4) * 8;
    unsigned short* dst = wstream + (size_t)f * 512 + l * 8;
#pragma unroll
    for (int j = 0; j < 8; j++) {
      int k = k0 + j;
      float v;
      if (k < 256)      v = W_hh[col * 256 + k];
      else if (k < 264) v = W_ih[col * 9 + (k - 256)];
      else              v = 0.0f;
      dst[j] = f2bf(v);
    }
  } else if (tid < 40960) {
    int t2 = tid - 36864;
    int f = t2 >> 6, l = t2 & 63;
    int nt = f >> 3, kt = f & 7;
    int col = nt * 16 + (l & 15);
    int k0 = kt * 32 + (l >> 4) * 8;
    unsigned short* dst = w1stream + (size_t)f * 512 + l * 8;
#pragma unroll
    for (int j = 0; j < 8; j++) dst[j] = f2bf(W1[col * 256 + k0 + j]);
  } else if (tid < 41984) {
    int g = tid - 40960;
    bias[g] = b_ih[g] + b_hh[g];
  } else if (tid < 43008) {
    int i = tid - 41984;
    pw[i] = W_ih[i * 9 + 8];               // prev-output column (rank-1)
  } else if (tid < 43008 + 131072) {
    pkt[tid - 43008] = 0ull;               // tag=0 never matches k>=1
  }
}

// ---------------- main: 8 WGs x 512 threads ----------------
__global__ __launch_bounds__(512, 1) void lstm_main(
    const float* __restrict__ x, const float* __restrict__ b1,
    const float* __restrict__ W2, const float* __restrict__ b2,
    const unsigned short* __restrict__ wstream, const unsigned short* __restrict__ w1stream,
    const float* __restrict__ bias, const float* __restrict__ pw,
    unsigned long long* __restrict__ pkt,
    float* __restrict__ out0, float* __restrict__ out1) {
  __shared__ unsigned short A[4][2][16][296];  // [group][slot][sample][K]
  __shared__ float part2[16][12];              // MLP partials [sample][wave]
  __shared__ unsigned short W1l[64 * 512];     // 64KB

  const int tid = threadIdx.x;
  const int w = tid >> 6, l = tid & 63, lr = l & 15, lg = l >> 4;
  const int set = blockIdx.x >> 1, hf = blockIdx.x & 1;
  const int myu = hf * 128 + w * 16 + lr;      // this lane's hidden unit

  // ---- persistent gate weights (wave w: all 4 gates of its 16 units) ----
  short8 wg_[36];
  {
    const short8* wp = (const short8*)wstream;
#pragma unroll
    for (int g = 0; g < 4; g++)
#pragma unroll
      for (int kt = 0; kt < 9; kt++)
        wg_[g * 9 + kt] = wp[(size_t)(hf * 288 + (g * 8 + w) * 9 + kt) * 64 + l];
  }
  {
    const unsigned long long* src = (const unsigned long long*)w1stream;
    unsigned long long* dstl = (unsigned long long*)W1l;
    for (int i = tid; i < 8192; i += 512) dstl[i] = src[i];
  }
  float biasv[4], pwv[4];
#pragma unroll
  for (int g = 0; g < 4; g++) {
    biasv[g] = bias[g * 256 + myu];
    pwv[g]   = pw[g * 256 + myu];
  }
  const float b1v = b1[w * 16 + lr];
  const float w2v = W2[w * 16 + lr];
  const float b2v = b2[0];

  float c4[4][4];                              // [group][r] cell states (j-loop unrolled)
#pragma unroll
  for (int j = 0; j < 4; j++)
#pragma unroll
    for (int r = 0; r < 4; r++) c4[j][r] = 0.f;

  for (int i = tid; i < 4 * 2 * 16 * 296; i += 512) ((unsigned short*)A)[i] = 0;

  // x prefetch: wave 7, thread t=tid-448: group xj=t>>4, sample xs=t&15
  const int xj = (tid - 448) >> 4, xs = tid & 15;
  f32x4 xa = {0.f,0.f,0.f,0.f}, xb = {0.f,0.f,0.f,0.f};
  if (tid >= 448) {
    const float* xp = x + (size_t)((set * 4 + xj) * 16 + xs) * LSEQ * 8;
    xa = *(const f32x4*)xp;
    xb = *(const f32x4*)(xp + 4);
  }
  __syncthreads();

  unsigned long long pv0 = 0, pv1 = 0;         // prefetched partner words

  for (int k = 0; k <= LSEQ; k++) {
    const int slot = k & 1;
#pragma unroll
    for (int j = 0; j < 4; j++) {
      const int g = set * 4 + j;
      const int n0 = g * 16;

      // ---- P1: receive partner h_{k-1} (prefetched) + stage x_k ----
      if (k > 0) {
        const unsigned long long* ba =
            pkt + ((((size_t)(k & 3) * 16 + g) * 2 + (hf ^ 1)) * 1024 + 2 * (size_t)tid);
        unsigned long long v0 = pv0, v1 = pv1;
        while ((unsigned)(v0 & 0xFFFFu) != (unsigned)k) v0 = agent_load(ba);
        while ((unsigned)(v1 & 0xFFFFu) != (unsigned)k) v1 = agent_load(ba + 1);
        unsigned long long pay = ((v0 >> 16) & 0xFFFFFFFFull)
                               | (((v1 >> 16) & 0xFFFFFFFFull) << 32);
        *(unsigned long long*)&A[j][slot][tid >> 5][(hf ^ 1) * 128 + 4 * (tid & 31)] = pay;
      }
      if (tid >= 448 && xj == j && k < LSEQ) {
        unsigned long long w0 = (unsigned long long)f2bf(xa.x)
                              | ((unsigned long long)f2bf(xa.y) << 16)
                              | ((unsigned long long)f2bf(xa.z) << 32)
                              | ((unsigned long long)f2bf(xa.w) << 48);
        unsigned long long w1w = (unsigned long long)f2bf(xb.x)
                               | ((unsigned long long)f2bf(xb.y) << 16)
                               | ((unsigned long long)f2bf(xb.z) << 32)
                               | ((unsigned long long)f2bf(xb.w) << 48);
        *(unsigned long long*)&A[j][slot][xs][256] = w0;
        *(unsigned long long*)&A[j][slot][xs][260] = w1w;
        if (k + 1 < LSEQ) {
          const float* xp = x + ((size_t)(n0 + xs) * LSEQ + (k + 1)) * 8;
          xa = *(const f32x4*)xp;
          xb = *(const f32x4*)(xp + 4);
        }
      }
      wg_barrier();   // B1: A[j][slot] complete

      // ---- P2: gate GEMM (in-register result) + MLP for out_{k-1} ----
      short8 afr[9];
#pragma unroll
      for (int kt = 0; kt < 9; kt++)
        afr[kt] = *(const short8*)&A[j][slot][lr][kt * 32 + lg * 8];
      f32x4 acc[4];
      if (k < LSEQ) {
#pragma unroll
        for (int gg = 0; gg < 4; gg++)
          acc[gg] = (f32x4){biasv[gg], biasv[gg], biasv[gg], biasv[gg]};
#pragma unroll
        for (int kt = 0; kt < 9; kt++) {
#pragma unroll
          for (int gg = 0; gg < 4; gg++)
            acc[gg] = __builtin_amdgcn_mfma_f32_16x16x32_bf16(afr[kt], wg_[gg * 9 + kt], acc[gg], 0, 0, 0);
        }
      }
      if (k > 0) {
        f32x4 m = {b1v, b1v, b1v, b1v};
#pragma unroll
        for (int kt = 0; kt < 8; kt++) {
          short8 wf = *(const short8*)&W1l[(w * 8 + kt) * 512 + l * 8];
          m = __builtin_amdgcn_mfma_f32_16x16x32_bf16(afr[kt], wf, m, 0, 0, 0);
        }
        float p[4];
#pragma unroll
        for (int r = 0; r < 4; r++) {
          float v = m[r] > 0.f ? m[r] : 0.f;
          p[r] = v * w2v;
          p[r] += __shfl_xor(p[r], 1, 64);
          p[r] += __shfl_xor(p[r], 2, 64);
          p[r] += __shfl_xor(p[r], 4, 64);
          p[r] += __shfl_xor(p[r], 8, 64);
        }
        if (lr == 0) {
#pragma unroll
          for (int r = 0; r < 4; r++) part2[lg * 4 + r][w] = p[r];
        }
      }
      wg_barrier();   // B2: part2 ready

      // ---- P3: out reduce + in-register cell update + publish + prefetch ----
      {
        float o4[4] = {0.f, 0.f, 0.f, 0.f};
        if (k > 0) {
#pragma unroll
          for (int r = 0; r < 4; r++) {
            const int s = lg * 4 + r;
            f32x4 pa = *(const f32x4*)&part2[s][0];
            f32x4 pb4 = *(const f32x4*)&part2[s][4];
            o4[r] = b2v + pa.x + pa.y + pa.z + pa.w + pb4.x + pb4.y + pb4.z + pb4.w;
          }
          if (hf == 0 && w == 0 && lr == 0) {
#pragma unroll
            for (int r = 0; r < 4; r++)
              __builtin_nontemporal_store(o4[r], out0 + (size_t)(n0 + lg * 4 + r) * LSEQ + (k - 1));
          }
        }
        if (k < LSEQ) {
          unsigned int hb[4];
#pragma unroll
          for (int r = 0; r < 4; r++) {
            float gi = acc[0][r] + pwv[0] * o4[r];
            float gf = acc[1][r] + pwv[1] * o4[r];
            float gg = acc[2][r] + pwv[2] * o4[r];
            float go = acc[3][r] + pwv[3] * o4[r];
            float c = sigm(gf) * c4[j][r] + sigm(gi) * tanh_(gg);
            c4[j][r] = c;
            float h = sigm(go) * tanh_(c);
            hb[r] = f2bf(h);
            __builtin_nontemporal_store(
                c, out1 + ((size_t)(n0 + lg * 4 + r) * LSEQ + k) * 256 + myu);
            A[j][slot ^ 1][lg * 4 + r][myu] = (unsigned short)hb[r];  // own-half
          }
          // publish: pair adjacent units via shfl; word = [h_odd|h_even|tag=k+1]
          unsigned int hx[4];
#pragma unroll
          for (int r = 0; r < 4; r++) hx[r] = (unsigned int)__shfl_xor((int)hb[r], 1, 64);
          unsigned long long* base =
              pkt + (((size_t)((k + 1) & 3) * 16 + g) * 2 + hf) * 1024;
          const int rb = (lr & 1) * 2;
#pragma unroll
          for (int d = 0; d < 2; d++) {
            const int r = rb + d;
            const unsigned int he = (lr & 1) ? hx[r] : hb[r];
            const unsigned int ho = (lr & 1) ? hb[r] : hx[r];
            unsigned long long wv = (unsigned long long)(unsigned)(k + 1)
                                  | ((unsigned long long)he << 16)
                                  | ((unsigned long long)ho << 32);
            agent_store(base + (lg * 4 + r) * 64 + w * 8 + (lr >> 1), wv);
          }
        }
        // prefetch next phase's partner words (use is 1 full phase away)
        int jn = j + 1, kn = k;
        if (jn == 4) { jn = 0; kn = k + 1; }
        if (kn > 0 && kn <= LSEQ) {
          const unsigned long long* nb =
              pkt + ((((size_t)(kn & 3) * 16 + (set * 4 + jn)) * 2 + (hf ^ 1)) * 1024
                     + 2 * (size_t)tid);
          pv0 = agent_load(nb);
          pv1 = agent_load(nb + 1);
        }
      }
      // no barrier: P3's part2 reads precede B1(next); part2 rewritten only
      // after that B1; A writes touch disjoint regions per phase.
    }
  }

  __builtin_amdgcn_fence(__ATOMIC_RELEASE, "agent");   // replay safety
}

extern "C" void kernel_launch(void* const* d_in, const int* in_sizes, int n_in,
                              void* d_out, int out_size, void* d_ws, size_t ws_size,
                              hipStream_t stream) {
  const float* x    = (const float*)d_in[0];
  const float* W_ih = (const float*)d_in[1];
  const float* W_hh = (const float*)d_in[2];
  const float* b_ih = (const float*)d_in[3];
  const float* b_hh = (const float*)d_in[4];
  const float* W1   = (const float*)d_in[5];
  const float* b1   = (const float*)d_in[6];
  const float* W2   = (const float*)d_in[7];
  const float* b2   = (const float*)d_in[8];

  unsigned short*     wstream  = (unsigned short*)d_ws;                      // 589,824 B
  unsigned short*     w1stream = (unsigned short*)((char*)d_ws + 589824);    // 65,536 B
  float*              bias     = (float*)((char*)d_ws + 655360);             // 4,096 B
  float*              pw       = (float*)((char*)d_ws + 659456);             // 4,096 B
  unsigned long long* pkt      = (unsigned long long*)((char*)d_ws + 663552);// 1,048,576 B

  float* out0 = (float*)d_out;            // [256,2048,1]
  float* out1 = out0 + 256 * LSEQ;        // [256,2048,256]

  prep_kernel<<<681, 256, 0, stream>>>(W_ih, W_hh, b_ih, b_hh, W1,
                                       wstream, w1stream, bias, pw, pkt);
  lstm_main<<<8, 512, 0, stream>>>(x, b1, W2, b2, wstream, w1stream, bias, pw,
                                   pkt, out0, out1);
}

// Round 13
// 7204.942 us; speedup vs baseline: 7.6744x; 7.6744x over previous
//
#include <hip/hip_runtime.h>

// LSTM: N=256, L=2048, IN=8, H1=256, H2=128, OUT=1
// 128 WGs = 16 batch-groups x 8 unit-slices; weights persistent in registers.
// R3's PROVEN LLC exchange (agent atomics, flag-spin + bulk packet read),
// with the publish path shortened: cell waves (0-3) publish their own packet
// quarter directly after the cell update (no hout staging, no wave-0 handoff),
// vmcnt-isolated ack, per-wave quarter-flags (4 x u32 in one 16B line).
// 2 barriers/step. No placement assumptions; no unbounded non-coherent spins.

typedef __attribute__((ext_vector_type(8))) short short8;
typedef __attribute__((ext_vector_type(4))) float f32x4;
typedef __attribute__((ext_vector_type(2))) float f32x2;

#define LSEQ 2048

__device__ __forceinline__ unsigned short f2bf(float f) {
  unsigned int u = __float_as_uint(f);
  return (unsigned short)((u + 0x7FFFu + ((u >> 16) & 1u)) >> 16);
}
__device__ __forceinline__ float sigm(float x) {
  float e = __builtin_amdgcn_exp2f(-1.44269504089f * x);
  return __builtin_amdgcn_rcpf(1.0f + e);
}
__device__ __forceinline__ float tanh_(float x) {
  float ax = __builtin_fabsf(x);
  float e = __builtin_amdgcn_exp2f(-2.88539008178f * ax);
  float t = (1.0f - e) * __builtin_amdgcn_rcpf(1.0f + e);
  return __builtin_copysignf(t, x);
}
__device__ __forceinline__ void wg_barrier() {
  __asm__ __volatile__("s_waitcnt lgkmcnt(0)" ::: "memory");
  __builtin_amdgcn_s_barrier();
}
__device__ __forceinline__ unsigned long long agent_load64(const unsigned long long* a) {
  return __hip_atomic_load(a, __ATOMIC_RELAXED, __HIP_MEMORY_SCOPE_AGENT);
}
__device__ __forceinline__ void agent_store32(unsigned int* a, unsigned int v) {
  __hip_atomic_store(a, v, __ATOMIC_RELAXED, __HIP_MEMORY_SCOPE_AGENT);
}

// ---------------- setup: swizzle weights (prev col zero; rank-1 at use) + zero flags ----------------
__global__ void prep_kernel(const float* __restrict__ W_ih, const float* __restrict__ W_hh,
                            const float* __restrict__ b_ih, const float* __restrict__ b_hh,
                            const float* __restrict__ W1,
                            unsigned short* __restrict__ wstream,
                            unsigned short* __restrict__ w1stream,
                            float* __restrict__ bias,
                            unsigned int* __restrict__ flags32) {
  int tid = blockIdx.x * 256 + threadIdx.x;
  if (tid < 36864) {                      // 576 gate fragments * 64 lanes
    int f = tid >> 6, l = tid & 63;
    int w = f / 72, rem = f % 72, nt = rem / 9, kt = rem % 9;
    int g = (nt >> 1) * 256 + w * 32 + (nt & 1) * 16 + (l & 15);
    int k0 = kt * 32 + (l >> 4) * 8;
    unsigned short* dst = wstream + (size_t)f * 512 + l * 8;
#pragma unroll
    for (int j = 0; j < 8; j++) {
      int k = k0 + j;
      float v;
      if (k < 256)       v = W_hh[g * 256 + k];
      else if (k < 264)  v = W_ih[g * 9 + (k - 256)];   // x columns only
      else               v = 0.0f;                       // prev handled rank-1
      dst[j] = f2bf(v);
    }
  } else if (tid < 36864 + 4096) {        // 64 W1 fragments
    int t2 = tid - 36864;
    int f = t2 >> 6, l = t2 & 63;
    int w = f >> 3, kt = f & 7;
    int h2 = w * 16 + (l & 15);
    int k0 = kt * 32 + (l >> 4) * 8;
    unsigned short* dst = w1stream + (size_t)f * 512 + l * 8;
#pragma unroll
    for (int j = 0; j < 8; j++) dst[j] = f2bf(W1[h2 * 256 + k0 + j]);
  } else if (tid < 36864 + 4096 + 1024) {
    int g = tid - 36864 - 4096;
    bias[g] = b_ih[g] + b_hh[g];
  } else if (tid < 36864 + 4096 + 1024 + 512) {
    flags32[tid - 41984] = 0u;            // 16 bg * 8 sl * 4 quarters
  }
}

// ---------------- main: 128 WGs x 512 threads ----------------
__global__ __launch_bounds__(512, 2) void lstm_main(
    const float* __restrict__ x, const float* __restrict__ W_ih,
    const float* __restrict__ b1, const float* __restrict__ W2, const float* __restrict__ b2,
    const unsigned short* __restrict__ wstream, const unsigned short* __restrict__ w1stream,
    const float* __restrict__ bias,
    unsigned long long* __restrict__ packets, unsigned int* __restrict__ flags32,
    float* __restrict__ out0, float* __restrict__ out1) {
  __shared__ unsigned short A[2][16][296];   // [slot][sample][K]: 0..255 h, 256..263 x, rest 0
  __shared__ float gbuf[4][16][34];          // [gate][sample][unit]
  __shared__ float part[8][17];              // MLP partials [wave][sample]

  const int tid = threadIdx.x;
  const int w = tid >> 6, l = tid & 63, lr = l & 15, lg = l >> 4;
  const int bg = blockIdx.x & 15, sl = blockIdx.x >> 4;
  const int n0 = bg * 16, u0 = sl * 32;

  // persistent weights in registers (17 frags = 68 regs, AGPR-backed)
  short8 wg_[9], w1_[8];
  {
    const short8* wp = (const short8*)wstream;
    const short8* w1p = (const short8*)w1stream;
#pragma unroll
    for (int kt = 0; kt < 9; kt++) wg_[kt] = wp[(size_t)((sl * 8 + w) * 9 + kt) * 64 + l];
#pragma unroll
    for (int kt = 0; kt < 8; kt++) w1_[kt] = w1p[(size_t)(w * 8 + kt) * 64 + l];
  }
  const float biasv = bias[(w >> 1) * 256 + u0 + (w & 1) * 16 + lr];
  const float b1v = b1[w * 16 + lr];
  const float w2v = W2[w * 16 + lr];
  const float b2v = b2[0];

  // cell lanes: waves 0..3 (tid<256): sample cs, unit pair u0+cu2, u0+cu2+1
  const int cs = tid >> 4, cu2 = (tid & 15) * 2;
  float wpv[8];
  float c0r = 0.f, c1r = 0.f;
  if (tid < 256) {
#pragma unroll
    for (int g = 0; g < 4; g++) {
      wpv[g * 2 + 0] = W_ih[(g * 256 + u0 + cu2) * 9 + 8];
      wpv[g * 2 + 1] = W_ih[(g * 256 + u0 + cu2 + 1) * 9 + 8];
    }
  }

  for (int i = tid; i < 2 * 16 * 296; i += 512) ((unsigned short*)A)[i] = 0;

  // x prefetch (wave sl, lanes 0..31: sample l>>1, half l&1)
  f32x4 xv = {0.f, 0.f, 0.f, 0.f};
  if (w == sl && l < 32)
    xv = *(const f32x4*)(x + (size_t)(n0 + (l >> 1)) * LSEQ * 8 + (l & 1) * 4);

  __syncthreads();   // init barrier

  for (int k = 0; k <= LSEQ; k++) {
    const int slot = k & 1;

    // ---- P1: stage x (wave sl) / flag-spin + bulk packet read (other waves) ----
    if (w == sl) {
      if (l < 32 && k < LSEQ) {
        unsigned long long xp = (unsigned long long)f2bf(xv.x)
                              | ((unsigned long long)f2bf(xv.y) << 16)
                              | ((unsigned long long)f2bf(xv.z) << 32)
                              | ((unsigned long long)f2bf(xv.w) << 48);
        *(unsigned long long*)&A[slot][l >> 1][256 + (l & 1) * 4] = xp;
        if (k + 1 < LSEQ)
          xv = *(const f32x4*)(x + ((size_t)(n0 + (l >> 1)) * LSEQ + (k + 1)) * 8 + (l & 1) * 4);
      }
    } else if (k > 0) {
      // spin on slice w's quarter-flag line (one 16B line, coalesced across lanes)
      const unsigned long long* fb = (const unsigned long long*)(flags32 + (bg * 8 + w) * 4);
      unsigned long long f0, f1;
      do {
        f0 = agent_load64(fb);
        f1 = agent_load64(fb + 1);
      } while ((unsigned)(f0 & 0xFFFFFFFFu) < (unsigned)k || (unsigned)(f0 >> 32) < (unsigned)k ||
               (unsigned)(f1 & 0xFFFFFFFFu) < (unsigned)k || (unsigned)(f1 >> 32) < (unsigned)k);
      const unsigned long long* pk = packets + (((size_t)slot * 16 + bg) * 8 + w) * 128 + l * 2;
      unsigned long long d0 = agent_load64(pk);
      unsigned long long d1 = agent_load64(pk + 1);
      unsigned long long* dst = (unsigned long long*)&A[slot][l >> 2][w * 32 + (l & 3) * 8];
      dst[0] = d0; dst[1] = d1;
    }
    wg_barrier();   // B1: A[slot] complete (h_{k-1} + x_k)

    // ---- P2: gate GEMM (k<LSEQ) + MLP for out_{k-1} (k>0), shared A-fragments ----
    short8 afr[9];
#pragma unroll
    for (int kt = 0; kt < 9; kt++)
      afr[kt] = *(const short8*)&A[slot][lr][kt * 32 + lg * 8];
    if (k < LSEQ) {
      f32x4 acc = {biasv, biasv, biasv, biasv};
#pragma unroll
      for (int kt = 0; kt < 9; kt++)
        acc = __builtin_amdgcn_mfma_f32_16x16x32_bf16(afr[kt], wg_[kt], acc, 0, 0, 0);
#pragma unroll
      for (int r = 0; r < 4; r++) gbuf[w >> 1][lg * 4 + r][(w & 1) * 16 + lr] = acc[r];
    }
    if (k > 0) {
      f32x4 m = {b1v, b1v, b1v, b1v};
#pragma unroll
      for (int kt = 0; kt < 8; kt++)
        m = __builtin_amdgcn_mfma_f32_16x16x32_bf16(afr[kt], w1_[kt], m, 0, 0, 0);
      float p[4];
#pragma unroll
      for (int r = 0; r < 4; r++) {
        float v = m[r] > 0.f ? m[r] : 0.f;
        p[r] = v * w2v;
        p[r] += __shfl_xor(p[r], 1, 64);
        p[r] += __shfl_xor(p[r], 2, 64);
        p[r] += __shfl_xor(p[r], 4, 64);
        p[r] += __shfl_xor(p[r], 8, 64);
      }
      if (lr == 0) {
#pragma unroll
        for (int r = 0; r < 4; r++) part[w][lg * 4 + r] = p[r];
      }
    }
    wg_barrier();   // B2: gbuf + part ready

    // ---- P3 (waves 0..3): in-lane out reduce + cell + DIRECT publish ----
    if (tid < 256) {
      float o = 0.f;
      if (k > 0) {
        o = b2v;
#pragma unroll
        for (int i = 0; i < 8; i++) o += part[i][cs];
      }
      if (k < LSEQ) {
        float gi0 = gbuf[0][cs][cu2] + wpv[0] * o, gi1 = gbuf[0][cs][cu2 + 1] + wpv[1] * o;
        float gf0 = gbuf[1][cs][cu2] + wpv[2] * o, gf1 = gbuf[1][cs][cu2 + 1] + wpv[3] * o;
        float gg0 = gbuf[2][cs][cu2] + wpv[4] * o, gg1 = gbuf[2][cs][cu2 + 1] + wpv[5] * o;
        float go0 = gbuf[3][cs][cu2] + wpv[6] * o, go1 = gbuf[3][cs][cu2 + 1] + wpv[7] * o;
        c0r = sigm(gf0) * c0r + sigm(gi0) * tanh_(gg0);
        c1r = sigm(gf1) * c1r + sigm(gi1) * tanh_(gg1);
        float h0 = sigm(go0) * tanh_(c0r);
        float h1 = sigm(go1) * tanh_(c1r);
        unsigned int hb0 = f2bf(h0), hb1 = f2bf(h1);
        unsigned int hb = hb0 | (hb1 << 16);

        // publish FIRST: one u32 agent store into next-slot packet
        unsigned int* pall = (unsigned int*)(packets +
            (((size_t)((k + 1) & 1) * 16 + bg) * 8 + sl) * 128);
        agent_store32(pall + cs * 16 + (cu2 >> 1), hb);
        // ack covers ONLY the packet store (c-stores issued after)
        __asm__ __volatile__("s_waitcnt vmcnt(0)" ::: "memory");
        if ((tid & 63) == 0)
          agent_store32(flags32 + (bg * 8 + sl) * 4 + w, (unsigned)(k + 1));

        // fire-and-forget tails (off the exchange critical path)
        f32x2 cv = {c0r, c1r};
        __builtin_nontemporal_store(cv,
            (f32x2*)(out1 + ((size_t)(n0 + cs) * LSEQ + k) * 256 + u0 + cu2));
        *(unsigned int*)&A[slot ^ 1][cs][u0 + cu2] = hb;   // own-slice short circuit
      }
      if (k > 0 && cu2 == 0 && sl == 0)
        __builtin_nontemporal_store(o, out0 + (size_t)(n0 + cs) * LSEQ + (k - 1));
    }
    // no barrier: P3 LDS reads precede own next-B1; gbuf/part rewritten only
    // after B1(k+1); A[slot^1] writer regions disjoint (own slice vs remote).
  }
}

extern "C" void kernel_launch(void* const* d_in, const int* in_sizes, int n_in,
                              void* d_out, int out_size, void* d_ws, size_t ws_size,
                              hipStream_t stream) {
  const float* x    = (const float*)d_in[0];
  const float* W_ih = (const float*)d_in[1];
  const float* W_hh = (const float*)d_in[2];
  const float* b_ih = (const float*)d_in[3];
  const float* b_hh = (const float*)d_in[4];
  const float* W1   = (const float*)d_in[5];
  const float* b1   = (const float*)d_in[6];
  const float* W2   = (const float*)d_in[7];
  const float* b2   = (const float*)d_in[8];

  unsigned short*     wstream  = (unsigned short*)d_ws;                        // 1,179,648 B
  unsigned short*     w1stream = (unsigned short*)((char*)d_ws + 1179648);     // 65,536 B
  float*              bias     = (float*)((char*)d_ws + 1245184);              // 4,096 B
  unsigned long long* packets  = (unsigned long long*)((char*)d_ws + 1249280); // 262,144 B
  unsigned int*       flags32  = (unsigned int*)((char*)d_ws + 1511424);       // 2,048 B

  float* out0 = (float*)d_out;            // [256,2048,1]
  float* out1 = out0 + 256 * LSEQ;        // [256,2048,256]

  prep_kernel<<<166, 256, 0, stream>>>(W_ih, W_hh, b_ih, b_hh, W1,
                                       wstream, w1stream, bias, flags32);
  lstm_main<<<128, 512, 0, stream>>>(x, W_ih, b1, W2, b2, wstream, w1stream, bias,
                                     packets, flags32, out0, out1);
}